// Round 2
// baseline (163.383 us; speedup 1.0000x reference)
//
#include <hip/hip_runtime.h>
#include <math.h>

// HungarianLoss: B=4096 independent 32x32 "LSA" problems + matched loss.
//
// IMPORTANT: the Python reference's _lsa_square is a buggy JV variant:
// it updates copies of minv/way and never writes them back. Net semantics:
//   for each row i (1..n):
//     j0 = 0; used = {}; (p[0] := i)
//     loop:
//       used += {j0}; i0 = p[j0]
//       over free cols j: cur_j = cost[i0-1][j] - u[i0] - v[j]   (float64)
//       j1 = argmin_j cur_j (first index on ties); delta = cur_{j1}
//       u[p[j]] += delta  for all used j   (tree rows, incl. p[0]=i)
//       v[j]    -= delta  for all used j
//       j0 = j1; if p[j0] == 0: break
//     p[j0] = i            // ONLY the terminal column is (re)assigned
// We replicate exactly, one wave per batch; lane r<->row r+1 (u), col r+1 (v,p).
// Lanes 32..63 mirror 0..31 so 64-lane shuffles are uniform.

constexpr int BB = 4096;
constexpr int NN = 32;
constexpr int TT = 8;
constexpr float ALPHA_F = 1.0f;
constexpr float BETA_F  = 0.5f;
constexpr float EPS_F   = 1e-8f;

__global__ __launch_bounds__(256) void hungarian_lsa_kernel(
    const float* __restrict__ pred_j,
    const float* __restrict__ logits,
    const float* __restrict__ target_j,
    const int*   __restrict__ target_types,
    double* __restrict__ partials)
{
    __shared__ float costS [4][NN * NN];  // 4 KB per wave
    __shared__ float logitS[4][NN * TT];  // raw logits
    __shared__ float logpS [4][NN * TT];  // log(softmax+eps)

    const int wave = threadIdx.x >> 6;
    const int lane = threadIdx.x & 63;
    const int col  = lane & 31;           // 0..31, duplicated in upper half
    const int b    = blockIdx.x * 4 + wave;

    float* cost = costS[wave];
    float* lgt  = logitS[wave];
    float* lgp  = logpS[wave];

    // ---- per-row data (lane r <-> row r) ----
    const float pj = pred_j  [b * NN + col];
    const float tj = target_j[b * NN + col];
    const int   tt = target_types[b * NN + col];

    float x[TT];
    const float* lrow = logits + ((size_t)b * NN + col) * TT;
#pragma unroll
    for (int t = 0; t < TT; ++t) x[t] = lrow[t];

    float m = x[0]; int am = 0;
#pragma unroll
    for (int t = 1; t < TT; ++t) { if (x[t] > m) { m = x[t]; am = t; } }
    float s = 0.f;
#pragma unroll
    for (int t = 0; t < TT; ++t) s += expf(x[t] - m);
    const float lse = m + logf(s);

    if (lane < 32) {
#pragma unroll
        for (int t = 0; t < TT; ++t) {
            float p = expf(x[t] - m) / s;
            lgp[col * TT + t] = logf(p + EPS_F);
            lgt[col * TT + t] = x[t];
        }
    }
    __syncthreads();

    // ---- cost[i][j] = |pj[i]-tj[j]| + 0.5*(-logp[i][tt[j]])  (f32, as ref) ----
    for (int i = 0; i < NN; ++i) {
        float pji = __shfl(pj, i);
        float lp  = lgp[i * TT + tt];
        float c   = ALPHA_F * fabsf(pji - tj) + BETA_F * (-lp);
        if (lane < 32) cost[i * NN + col] = c;
    }
    __syncthreads();

    // ---- reference's degenerate shortest-path walk, f64 duals ----
    const double INF = (double)INFINITY;
    double u_d = 0.0;   // u[col+1]  (row potential; lane r <-> row r+1)
    double v_d = 0.0;   // v[col+1]  (column potential)
    int    p_i = 0;     // row assigned to column col+1 (1-based), 0 = none

    for (int i = 1; i <= NN; ++i) {
        bool used_b  = false;   // column col+1 used this round
        bool in_tree = false;   // row col+1 in the alternating tree
        int  j0 = 0;
        for (;;) {
            if (col == j0 - 1) used_b = true;               // j0 >= 1 only
            const int i0 = (j0 == 0) ? i : __shfl(p_i, j0 - 1);
            if (col == i0 - 1) in_tree = true;
            const double u_i0 = __shfl(u_d, i0 - 1);
            const double cur  = ((double)cost[(i0 - 1) * NN + col] - u_i0) - v_d;

            // argmin over free columns, smallest index on ties (np.argmin)
            double mval = used_b ? INF : cur;
            int    mcol = col;
#pragma unroll
            for (int off = 32; off >= 1; off >>= 1) {
                double ov = __shfl_xor(mval, off);
                int    oc = __shfl_xor(mcol, off);
                if (ov < mval || (ov == mval && oc < mcol)) { mval = ov; mcol = oc; }
            }
            const double delta = mval;          // wave-uniform
            const int    j1    = mcol + 1;      // wave-uniform

            if (in_tree) u_d += delta;          // u[p[used]] += delta
            if (used_b)  v_d -= delta;          // v[used]    -= delta

            j0 = j1;
            const int pj0 = __shfl(p_i, j0 - 1);
            if (pj0 == 0) break;
        }
        if (col == j0 - 1) p_i = i;             // only terminal column assigned
    }

    // ---- matched loss contributions (column-centric; bijection == row sum) ----
    const int   row      = p_i - 1;
    const float pj_row   = __shfl(pj,  row);
    const float lse_row  = __shfl(lse, row);
    const int   am_row   = __shfl(am,  row);
    const float logit_tt = lgt[row * TT + tt];

    double sj = (lane < 32) ? (double)fabsf(pj_row - tj)      : 0.0;
    double st = (lane < 32) ? (double)(lse_row - logit_tt)    : 0.0;
    double sa = (lane < 32) ? ((am_row == tt) ? 1.0 : 0.0)    : 0.0;
#pragma unroll
    for (int off = 32; off >= 1; off >>= 1) {
        sj += __shfl_xor(sj, off);
        st += __shfl_xor(st, off);
        sa += __shfl_xor(sa, off);
    }
    if (lane == 0) {
        partials[b * 3 + 0] = sj;
        partials[b * 3 + 1] = st;
        partials[b * 3 + 2] = sa;
    }
}

__global__ __launch_bounds__(256) void hungarian_finalize_kernel(
    const double* __restrict__ partials, float* __restrict__ out)
{
    __shared__ double sm0[256], sm1[256], sm2[256];
    const int tid = threadIdx.x;
    double a = 0.0, c = 0.0, e = 0.0;
    for (int i = tid; i < BB; i += 256) {
        a += partials[i * 3 + 0];
        c += partials[i * 3 + 1];
        e += partials[i * 3 + 2];
    }
    sm0[tid] = a; sm1[tid] = c; sm2[tid] = e;
    __syncthreads();
    for (int s = 128; s > 0; s >>= 1) {
        if (tid < s) {
            sm0[tid] += sm0[tid + s];
            sm1[tid] += sm1[tid + s];
            sm2[tid] += sm2[tid + s];
        }
        __syncthreads();
    }
    if (tid == 0) {
        const double jl = sm0[0], tl = sm1[0], ac = sm2[0];
        const double total = (double)BB * (double)NN;
        out[0] = (float)((jl + 0.5 * tl) / total);  // loss
        out[1] = (float)(jl / total);               // j_mae
        out[2] = (float)(ac / total);               // type_acc
    }
}

extern "C" void kernel_launch(void* const* d_in, const int* in_sizes, int n_in,
                              void* d_out, int out_size, void* d_ws, size_t ws_size,
                              hipStream_t stream) {
    const float* pred_j       = (const float*)d_in[0];
    const float* logits       = (const float*)d_in[1];
    const float* target_j     = (const float*)d_in[2];
    const int*   target_types = (const int*)  d_in[3];
    // d_in[4], d_in[5] are all-ones masks, unused by the reference math.

    double* partials = (double*)d_ws;   // 4096*3 doubles = 96 KB
    float*  out      = (float*)d_out;

    hungarian_lsa_kernel<<<BB / 4, 256, 0, stream>>>(
        pred_j, logits, target_j, target_types, partials);
    hungarian_finalize_kernel<<<1, 256, 0, stream>>>(partials, out);
}

// Round 6
// 49.534 us; speedup vs baseline: 3.2984x; 3.2984x over previous
//
#include <hip/hip_runtime.h>
#include <math.h>

// HungarianLoss: B=4096 independent 32x32 degenerate-JV problems + matched loss.
// One wave per batch; lane <-> column (duplicated into lanes 32..63).
//
// Reference semantics (its _lsa_square never writes back minv/way):
//   for row i: j0=0; used={}; p[0]=i
//     loop: used+={j0}; i0=p[j0]
//           j1 = argmin_{free j}(cost[i0-1][j] - u[i0] - v[j]); delta = that min
//           u[p[used]] += delta; v[used] -= delta
//           j0=j1; if p[j0]==0 break
//     p[j0] = i   // only terminal column assigned
//
// Optimizations (exact algebra, f32 duals):
//  - u[i0] is a uniform shift -> argmin over (cost[i0][j] - v[j]) only.
//  - costByCol[j][col] = cost[p[j]-1][col], written once per walk ->
//    no shfl(p) on the critical path; break test via SGPR bitmask amask.
//  - uc[col] = u[p[col+1]] mirrors v updates (same used-set, +delta vs -delta).
//  - 32-lane min via DPP (VALU latency) + readlane; argmin tie-break via
//    ballot+ffs (lowest col, == np.argmin).

constexpr int BB = 4096;
constexpr int NN = 32;
constexpr int TT = 8;
constexpr float ALPHA_F = 1.0f;
constexpr float BETA_F  = 0.5f;
constexpr float EPS_F   = 1e-8f;

template <int CTRL, int ROW_MASK>
__device__ __forceinline__ float dpp_min(float x) {
    int t = __builtin_amdgcn_update_dpp(__float_as_int(x), __float_as_int(x),
                                        CTRL, ROW_MASK, 0xf, false);
    return fminf(x, __int_as_float(t));
}

// Min over each 32-lane half (halves hold identical data); broadcast via SGPR.
__device__ __forceinline__ float wave32_min_bcast(float x) {
    x = dpp_min<0xB1,  0xf>(x); // quad_perm [1,0,3,2]  (xor 1)
    x = dpp_min<0x4E,  0xf>(x); // quad_perm [2,3,0,1]  (xor 2)
    x = dpp_min<0x124, 0xf>(x); // row_ror:4
    x = dpp_min<0x128, 0xf>(x); // row_ror:8   -> per-16-row min
    x = dpp_min<0x142, 0xa>(x); // row_bcast15 -> rows 1,3 have 32-min
    return __int_as_float(__builtin_amdgcn_readlane(__float_as_int(x), 31));
}

__global__ __launch_bounds__(256) void hungarian_lsa_kernel(
    const float* __restrict__ pred_j,
    const float* __restrict__ logits,
    const float* __restrict__ target_j,
    const int*   __restrict__ target_types,
    double* __restrict__ partials)
{
    __shared__ float costS[4][NN * NN];   // cost row-major, 4 KB/wave
    __shared__ float cbcS [4][NN * NN];   // costByCol; aliases lgp during build
    __shared__ float lgtS [4][NN * TT];   // raw logits for epilogue gather

    const int wave = threadIdx.x >> 6;
    const int lane = threadIdx.x & 63;
    const int col  = lane & 31;
    const int b    = blockIdx.x * 4 + wave;

    float* cost = costS[wave];
    float* cbc  = cbcS[wave];
    float* lgp  = cbcS[wave];             // alias; dead after cost build
    float* lgt  = lgtS[wave];

    // ---- per-lane row data (lane r <-> row r) ----
    const float pj = pred_j  [b * NN + col];
    const float tj = target_j[b * NN + col];
    const int   tt = target_types[b * NN + col];

    float x[TT];
    const float* lrow = logits + ((size_t)b * NN + col) * TT;
#pragma unroll
    for (int t = 0; t < TT; ++t) x[t] = lrow[t];

    float m = x[0]; int am = 0;
#pragma unroll
    for (int t = 1; t < TT; ++t) { if (x[t] > m) { m = x[t]; am = t; } }
    float s = 0.f;
#pragma unroll
    for (int t = 0; t < TT; ++t) s += expf(x[t] - m);
    const float lse = m + logf(s);

    if (lane < 32) {
#pragma unroll
        for (int t = 0; t < TT; ++t) {
            float p = expf(x[t] - m) / s;
            lgp[col * TT + t] = logf(p + EPS_F);
            lgt[col * TT + t] = x[t];
        }
    }
    __syncthreads();

    // ---- cost[i][j] = |pj[i]-tj[j]| + 0.5*(-logp[i][tt[j]])  (f32, as ref) ----
    for (int i = 0; i < NN; ++i) {
        float pji = __shfl(pj, i);
        float lp  = lgp[i * TT + tt];
        float c   = ALPHA_F * fabsf(pji - tj) + BETA_F * (-lp);
        if (lane < 32) cost[i * NN + col] = c;
    }
    __syncthreads();

    // ---- degenerate shortest-path walks ----
    const float INFF = __builtin_inff();
    float v_f  = 0.0f;    // v[col+1]
    float uc_f = 0.0f;    // u[p[col+1]] (valid once col assigned)
    int   p_i  = 0;       // row assigned to col+1 (1-based)
    unsigned amask = 0;   // bit j-1 set <=> col j assigned (wave-uniform)

    float cr = cost[col]; // prefetched cost[i-1][col] for current walk's new row

    for (int i = 1; i <= NN; ++i) {
        bool used_b = false;

        // step 0: i0 = i (new row), no cols used yet, u[i]=0
        float cur = cr - v_f;
        float mv  = wave32_min_bcast(cur);
        unsigned long long bm = __ballot(cur == mv);
        int   j1      = __ffsll(bm);       // 1-based col (lowest lane = lowest col)
        float rowSum  = mv;                // u[i] accumulates every delta this walk

        while ((amask >> (j1 - 1)) & 1u) { // chosen col occupied -> continue walk
            const int j0 = j1;
            used_b |= (col == j0 - 1);
            const float uc_j0 = __shfl(uc_f, j0 - 1);      // off critical path
            const float cur2  = cbc[(j0 - 1) * NN + col] - v_f;
            const float curm  = used_b ? INFF : cur2;
            mv = wave32_min_bcast(curm);
            bm = __ballot((!used_b) && (cur2 == mv));
            j1 = __ffsll(bm);
            const float delta = mv - uc_j0;
            rowSum += delta;
            if (used_b) { v_f -= delta; uc_f += delta; }
        }

        // terminal column j1: assign row i
        if (col == j1 - 1) { p_i = i; uc_f = rowSum; }
        amask |= 1u << (j1 - 1);
        cbc[(j1 - 1) * NN + col] = cr;        // costByCol for future walks
        cr = cost[min(i, NN - 1) * NN + col]; // prefetch next walk's row
    }

    // ---- matched loss contributions (column-centric; bijection == row sum) ----
    const int   row      = p_i - 1;
    const float pj_row   = __shfl(pj,  row);
    const float lse_row  = __shfl(lse, row);
    const int   am_row   = __shfl(am,  row);
    const float logit_tt = lgt[row * TT + tt];

    double sj = (lane < 32) ? (double)fabsf(pj_row - tj)   : 0.0;
    double st = (lane < 32) ? (double)(lse_row - logit_tt) : 0.0;
    double sa = (lane < 32) ? ((am_row == tt) ? 1.0 : 0.0) : 0.0;
#pragma unroll
    for (int off = 32; off >= 1; off >>= 1) {
        sj += __shfl_xor(sj, off);
        st += __shfl_xor(st, off);
        sa += __shfl_xor(sa, off);
    }
    if (lane == 0) {
        partials[b * 3 + 0] = sj;
        partials[b * 3 + 1] = st;
        partials[b * 3 + 2] = sa;
    }
}

__global__ __launch_bounds__(256) void hungarian_finalize_kernel(
    const double* __restrict__ partials, float* __restrict__ out)
{
    __shared__ double sm0[256], sm1[256], sm2[256];
    const int tid = threadIdx.x;
    double a = 0.0, c = 0.0, e = 0.0;
    for (int i = tid; i < BB; i += 256) {
        a += partials[i * 3 + 0];
        c += partials[i * 3 + 1];
        e += partials[i * 3 + 2];
    }
    sm0[tid] = a; sm1[tid] = c; sm2[tid] = e;
    __syncthreads();
    for (int s = 128; s > 0; s >>= 1) {
        if (tid < s) {
            sm0[tid] += sm0[tid + s];
            sm1[tid] += sm1[tid + s];
            sm2[tid] += sm2[tid + s];
        }
        __syncthreads();
    }
    if (tid == 0) {
        const double jl = sm0[0], tl = sm1[0], ac = sm2[0];
        const double total = (double)BB * (double)NN;
        out[0] = (float)((jl + 0.5 * tl) / total);  // loss
        out[1] = (float)(jl / total);               // j_mae
        out[2] = (float)(ac / total);               // type_acc
    }
}

extern "C" void kernel_launch(void* const* d_in, const int* in_sizes, int n_in,
                              void* d_out, int out_size, void* d_ws, size_t ws_size,
                              hipStream_t stream) {
    const float* pred_j       = (const float*)d_in[0];
    const float* logits       = (const float*)d_in[1];
    const float* target_j     = (const float*)d_in[2];
    const int*   target_types = (const int*)  d_in[3];

    double* partials = (double*)d_ws;   // 4096*3 doubles = 96 KB
    float*  out      = (float*)d_out;

    hungarian_lsa_kernel<<<BB / 4, 256, 0, stream>>>(
        pred_j, logits, target_j, target_types, partials);
    hungarian_finalize_kernel<<<1, 256, 0, stream>>>(partials, out);
}